// Round 2
// baseline (256.989 us; speedup 1.0000x reference)
//
#include <hip/hip_runtime.h>

#define EPSV 1e-5f

__device__ __forceinline__ float block_reduce_sum(float v, float* lds) {
  #pragma unroll
  for (int off = 32; off > 0; off >>= 1) v += __shfl_down(v, off, 64);
  int lane = threadIdx.x & 63;
  int wid  = threadIdx.x >> 6;
  __syncthreads();
  if (lane == 0) lds[wid] = v;
  __syncthreads();
  float r = 0.f;
  if (threadIdx.x == 0) {
    int nw = blockDim.x >> 6;
    for (int i = 0; i < nw; ++i) r += lds[i];
  }
  return r;
}

// K1: conv1 (recomputed) + per-channel sum/sumsq partials.
__global__ __launch_bounds__(256) void k1_conv1_stats(
    const float* __restrict__ x, const float* __restrict__ w1, const float* __restrict__ b1,
    float* __restrict__ partials /* [16][2][1024] */) {
  __shared__ float lds[4];
  float sum[16], sq[16];
  #pragma unroll
  for (int c = 0; c < 16; ++c) { sum[c] = 0.f; sq[c] = 0.f; }
  const int total = 1024 * 32 * 32;
  for (int e = blockIdx.x * blockDim.x + threadIdx.x; e < total; e += gridDim.x * blockDim.x) {
    int wq = e & 31; int t = e >> 5; int hq = t & 31; int b = t >> 5;
    float xv[3][3][3];
    #pragma unroll
    for (int ci = 0; ci < 3; ++ci) {
      const float* xb = x + (b * 3 + ci) * 1024;
      #pragma unroll
      for (int dy = 0; dy < 3; ++dy) {
        int r = hq + dy - 1;
        #pragma unroll
        for (int dx = 0; dx < 3; ++dx) {
          int cpos = wq + dx - 1;
          xv[ci][dy][dx] = (r >= 0 && r < 32 && cpos >= 0 && cpos < 32) ? xb[r * 32 + cpos] : 0.f;
        }
      }
    }
    #pragma unroll
    for (int co = 0; co < 16; ++co) {
      float a = b1[co];
      #pragma unroll
      for (int ci = 0; ci < 3; ++ci)
        #pragma unroll
        for (int ky = 0; ky < 3; ++ky)
          #pragma unroll
          for (int kx = 0; kx < 3; ++kx)
            a = fmaf(xv[ci][ky][kx], w1[((co * 3 + ci) * 3 + ky) * 3 + kx], a);
      sum[co] += a;
      sq[co]  += a * a;
    }
  }
  for (int c = 0; c < 16; ++c) {
    float s = block_reduce_sum(sum[c], lds);
    float q = block_reduce_sum(sq[c], lds);
    if (threadIdx.x == 0) {
      partials[(c * 2 + 0) * gridDim.x + blockIdx.x] = s;
      partials[(c * 2 + 1) * gridDim.x + blockIdx.x] = q;
    }
  }
}

// K2/K6: reduce partials -> scale/shift per channel.
__global__ __launch_bounds__(256) void k_bn_finalize(
    const float* __restrict__ partials, int nb, float invN,
    const float* __restrict__ gamma, const float* __restrict__ beta,
    float* __restrict__ stats, int C) {
  __shared__ float lds[4];
  int c = blockIdx.x;
  float s = 0.f, q = 0.f;
  for (int i = threadIdx.x; i < nb; i += blockDim.x) {
    s += partials[(c * 2 + 0) * nb + i];
    q += partials[(c * 2 + 1) * nb + i];
  }
  s = block_reduce_sum(s, lds);
  q = block_reduce_sum(q, lds);
  if (threadIdx.x == 0) {
    float mean = s * invN;
    float var  = q * invN - mean * mean;
    float scale = gamma[c] * rsqrtf(var + EPSV);
    stats[c]     = scale;
    stats[C + c] = beta[c] - mean * scale;
  }
}

// K3: conv1 (recomputed) + BN + ReLU + basis_pool(K=2) -> h1 [1024,32,16,16]
__global__ __launch_bounds__(256) void k3_pool1(
    const float* __restrict__ x, const float* __restrict__ w1, const float* __restrict__ b1,
    const float* __restrict__ stats1, const float* __restrict__ pw, const float* __restrict__ pb,
    float* __restrict__ h1) {
  int e = blockIdx.x * 256 + threadIdx.x;
  int ow = e & 15; int t = e >> 4; int oh = t & 15; int b = t >> 4;
  float xv[3][4][4];
  #pragma unroll
  for (int ci = 0; ci < 3; ++ci) {
    const float* xb = x + (b * 3 + ci) * 1024;
    #pragma unroll
    for (int dy = 0; dy < 4; ++dy) {
      int r = 2 * oh - 1 + dy;
      #pragma unroll
      for (int dx = 0; dx < 4; ++dx) {
        int cpos = 2 * ow - 1 + dx;
        xv[ci][dy][dx] = (r >= 0 && r < 32 && cpos >= 0 && cpos < 32) ? xb[r * 32 + cpos] : 0.f;
      }
    }
  }
  float pw0 = pw[0] * 10.f, pw1 = pw[1] * 10.f;
  float pb0 = pb[0] * 10.f, pb1 = pb[1] * 10.f;
  for (int c = 0; c < 16; ++c) {
    float scale = stats1[c], shift = stats1[16 + c];
    float v[4];
    #pragma unroll
    for (int p = 0; p < 4; ++p) {
      int dh = p >> 1, dw = p & 1;
      float a = b1[c];
      #pragma unroll
      for (int ci = 0; ci < 3; ++ci)
        #pragma unroll
        for (int ky = 0; ky < 3; ++ky)
          #pragma unroll
          for (int kx = 0; kx < 3; ++kx)
            a = fmaf(xv[ci][dh + ky][dw + kx], w1[((c * 3 + ci) * 3 + ky) * 3 + kx], a);
      a = fmaf(a, scale, shift);
      v[p] = fmaxf(a, 0.f);
    }
    #pragma unroll
    for (int k = 0; k < 2; ++k) {
      float cw = k ? pw1 : pw0;
      float cb = k ? pb1 : pb0;
      float s0 = fmaf(v[0], cw, cb), s1 = fmaf(v[1], cw, cb);
      float s2 = fmaf(v[2], cw, cb), s3 = fmaf(v[3], cw, cb);
      float m = fmaxf(fmaxf(s0, s1), fmaxf(s2, s3));
      float e0 = expf(s0 - m), e1 = expf(s1 - m), e2 = expf(s2 - m), e3 = expf(s3 - m);
      float den = e0 + e1 + e2 + e3;
      float outv = (v[0] * e0 + v[1] * e1 + v[2] * e2 + v[3] * e3) / den;
      h1[((b * 32 + (c * 2 + k)) * 16 + oh) * 16 + ow] = outv;
    }
  }
}

// K4: conv2 direct; 4 output channels per thread; blockIdx.y = co-group (uniform -> scalar weights).
__global__ __launch_bounds__(256) void k4_conv2(
    const float* __restrict__ h1, const float* __restrict__ w2, const float* __restrict__ b2,
    float* __restrict__ y2) {
  int e = blockIdx.x * 256 + threadIdx.x;
  int wq = e & 15; int t = e >> 4; int hq = t & 15; int b = t >> 4;  // FIXED: was t >> 8
  int co0 = blockIdx.y * 4;
  float acc0 = b2[co0], acc1 = b2[co0 + 1], acc2 = b2[co0 + 2], acc3 = b2[co0 + 3];
  for (int ci = 0; ci < 32; ++ci) {
    const float* hb = h1 + (b * 32 + ci) * 256;
    float xv[9];
    #pragma unroll
    for (int ky = 0; ky < 3; ++ky) {
      int r = hq + ky - 1;
      #pragma unroll
      for (int kx = 0; kx < 3; ++kx) {
        int cpos = wq + kx - 1;
        xv[ky * 3 + kx] = (r >= 0 && r < 16 && cpos >= 0 && cpos < 16) ? hb[r * 16 + cpos] : 0.f;
      }
    }
    const float* wp = w2 + (co0 * 32 + ci) * 9;
    #pragma unroll
    for (int kk = 0; kk < 9; ++kk) {
      acc0 = fmaf(xv[kk], wp[kk], acc0);
      acc1 = fmaf(xv[kk], wp[288 + kk], acc1);
      acc2 = fmaf(xv[kk], wp[576 + kk], acc2);
      acc3 = fmaf(xv[kk], wp[864 + kk], acc3);
    }
  }
  int ob = (b * 32 + co0) * 256 + hq * 16 + wq;
  y2[ob]       = acc0;
  y2[ob + 256] = acc1;
  y2[ob + 512] = acc2;
  y2[ob + 768] = acc3;
}

// K5: per-channel stats of y2.
__global__ __launch_bounds__(256) void k5_stats_y2(
    const float* __restrict__ y2, float* __restrict__ partials) {
  __shared__ float lds[4];
  int c = blockIdx.y;
  float s = 0.f, q = 0.f;
  const int total = 1024 * 256;
  for (int e = blockIdx.x * blockDim.x + threadIdx.x; e < total; e += gridDim.x * blockDim.x) {
    int b = e >> 8, sp = e & 255;
    float v = y2[(b * 32 + c) * 256 + sp];
    s += v; q += v * v;
  }
  s = block_reduce_sum(s, lds);
  q = block_reduce_sum(q, lds);
  if (threadIdx.x == 0) {
    partials[(c * 2 + 0) * gridDim.x + blockIdx.x] = s;
    partials[(c * 2 + 1) * gridDim.x + blockIdx.x] = q;
  }
}

// K7: BN + ReLU + basis_pool2 -> h2 [1024,64,8,8]; one thread per (b,oh,ow).
__global__ __launch_bounds__(256) void k7_pool2(
    const float* __restrict__ y2, const float* __restrict__ stats2,
    const float* __restrict__ pw, const float* __restrict__ pb,
    float* __restrict__ h2) {
  int e = blockIdx.x * 256 + threadIdx.x;
  int ow = e & 7; int t = e >> 3; int oh = t & 7; int b = t >> 3;
  float pw0 = pw[0] * 10.f, pw1 = pw[1] * 10.f;
  float pb0 = pb[0] * 10.f, pb1 = pb[1] * 10.f;
  for (int c = 0; c < 32; ++c) {
    float scale = stats2[c], shift = stats2[32 + c];
    const float* yb = y2 + (b * 32 + c) * 256 + (2 * oh) * 16 + 2 * ow;
    float v0 = fmaxf(fmaf(yb[0],  scale, shift), 0.f);
    float v1 = fmaxf(fmaf(yb[1],  scale, shift), 0.f);
    float v2 = fmaxf(fmaf(yb[16], scale, shift), 0.f);
    float v3 = fmaxf(fmaf(yb[17], scale, shift), 0.f);
    #pragma unroll
    for (int k = 0; k < 2; ++k) {
      float cw = k ? pw1 : pw0;
      float cb = k ? pb1 : pb0;
      float s0 = fmaf(v0, cw, cb), s1 = fmaf(v1, cw, cb);
      float s2 = fmaf(v2, cw, cb), s3 = fmaf(v3, cw, cb);
      float m = fmaxf(fmaxf(s0, s1), fmaxf(s2, s3));
      float e0 = expf(s0 - m), e1 = expf(s1 - m), e2 = expf(s2 - m), e3 = expf(s3 - m);
      float den = e0 + e1 + e2 + e3;
      float outv = (v0 * e0 + v1 * e1 + v2 * e2 + v3 * e3) / den;
      h2[((b * 64 + (c * 2 + k)) * 8 + oh) * 8 + ow] = outv;
    }
  }
}

// K8: FC [1024,4096] x [10,4096]^T + b -> out [1024,10]; one block per row.
__global__ __launch_bounds__(256) void k8_fc(
    const float* __restrict__ h2, const float* __restrict__ fcw,
    const float* __restrict__ fcb, float* __restrict__ out) {
  __shared__ float lds[40];
  int b = blockIdx.x;
  float acc[10];
  #pragma unroll
  for (int j = 0; j < 10; ++j) acc[j] = 0.f;
  const float* hb = h2 + b * 4096;
  for (int i = threadIdx.x; i < 4096; i += 256) {
    float hv = hb[i];
    #pragma unroll
    for (int j = 0; j < 10; ++j) acc[j] = fmaf(hv, fcw[j * 4096 + i], acc[j]);
  }
  int lane = threadIdx.x & 63, wid = threadIdx.x >> 6;
  #pragma unroll
  for (int j = 0; j < 10; ++j) {
    float v = acc[j];
    #pragma unroll
    for (int off = 32; off > 0; off >>= 1) v += __shfl_down(v, off, 64);
    if (lane == 0) lds[wid * 10 + j] = v;
  }
  __syncthreads();
  if (threadIdx.x < 10) {
    float r = lds[threadIdx.x] + lds[10 + threadIdx.x] + lds[20 + threadIdx.x] +
              lds[30 + threadIdx.x] + fcb[threadIdx.x];
    out[b * 10 + threadIdx.x] = r;
  }
}

extern "C" void kernel_launch(void* const* d_in, const int* in_sizes, int n_in,
                              void* d_out, int out_size, void* d_ws, size_t ws_size,
                              hipStream_t stream) {
  (void)in_sizes; (void)n_in; (void)out_size; (void)ws_size;
  const float* x   = (const float*)d_in[0];
  const float* w1  = (const float*)d_in[1];
  const float* b1  = (const float*)d_in[2];
  const float* g1  = (const float*)d_in[3];
  const float* be1 = (const float*)d_in[4];
  const float* pw1 = (const float*)d_in[5];
  const float* pb1 = (const float*)d_in[6];
  const float* w2  = (const float*)d_in[7];
  const float* b2  = (const float*)d_in[8];
  const float* g2  = (const float*)d_in[9];
  const float* be2 = (const float*)d_in[10];
  const float* pw2 = (const float*)d_in[11];
  const float* pb2 = (const float*)d_in[12];
  const float* fcw = (const float*)d_in[13];
  const float* fcb = (const float*)d_in[14];
  float* out = (float*)d_out;

  char* ws = (char*)d_ws;
  float* h1       = (float*)(ws);                         // 32 MiB
  float* y2       = (float*)(ws + 33554432);              // 32 MiB
  float* h2       = (float*)(ws);                         // reuse of h1 space (16 MiB)
  float* partials = (float*)(ws + 67108864);              // 128 KiB
  float* stats1   = (float*)(ws + 67108864 + 131072);     // 32 floats
  float* stats2   = stats1 + 32;                          // 64 floats

  k1_conv1_stats<<<1024, 256, 0, stream>>>(x, w1, b1, partials);
  k_bn_finalize<<<16, 256, 0, stream>>>(partials, 1024, 1.f / 1048576.f, g1, be1, stats1, 16);
  k3_pool1<<<1024, 256, 0, stream>>>(x, w1, b1, stats1, pw1, pb1, h1);
  dim3 g4(1024, 8);
  k4_conv2<<<g4, 256, 0, stream>>>(h1, w2, b2, y2);
  dim3 g5(64, 32);
  k5_stats_y2<<<g5, 256, 0, stream>>>(y2, partials);
  k_bn_finalize<<<32, 256, 0, stream>>>(partials, 64, 1.f / 262144.f, g2, be2, stats2, 32);
  k7_pool2<<<256, 256, 0, stream>>>(y2, stats2, pw2, pb2, h2);
  k8_fc<<<1024, 256, 0, stream>>>(h2, fcw, fcb, out);
}